// Round 4
// baseline (159.433 us; speedup 1.0000x reference)
//
#include <hip/hip_runtime.h>

#define NROWS 4096
#define DIM   512
#define MARGIN 0.2f
#define EPS 1e-6f
#define BIG 1e9f
#define NTILES 64               // 4096 / 64
#define NBLOCKS 2080            // 64*65/2 triangle tiles
#define BPX 260                 // NBLOCKS / 8 (XCD swizzle)

typedef __attribute__((ext_vector_type(8))) short bf16x8;
typedef __attribute__((ext_vector_type(4))) float f32x4;

// monotone float <-> uint mapping (order-preserving), for atomicMax/Min on floats
__device__ __forceinline__ unsigned enc_f(float x) {
    unsigned u = __float_as_uint(x);
    return (u & 0x80000000u) ? ~u : (u | 0x80000000u);
}
__device__ __forceinline__ float dec_f(unsigned u) {
    return (u & 0x80000000u) ? __uint_as_float(u ^ 0x80000000u) : __uint_as_float(~u);
}

__device__ __forceinline__ unsigned short f2bf_rne(float x) {
    unsigned u = __float_as_uint(x);
    unsigned r = u + 0x7FFFu + ((u >> 16) & 1u);
    return (unsigned short)(r >> 16);
}

// split f32 feats into bf16 hi + lo; also init hp/hn and the done-counter
__global__ void prep_kernel(const float* __restrict__ feats,
                            unsigned short* __restrict__ fhi,
                            unsigned short* __restrict__ flo,
                            unsigned* __restrict__ hp,
                            unsigned* __restrict__ hn,
                            unsigned* __restrict__ counter) {
    const int gid = blockIdx.x * 256 + threadIdx.x;
    if (gid < NROWS) {
        hp[gid] = enc_f(-BIG);
        hn[gid] = enc_f(BIG);
    }
    if (gid == 0) *counter = 0u;
    const int i = gid * 4;
    const float4 v = *(const float4*)&feats[i];
    float x[4] = {v.x, v.y, v.z, v.w};
    unsigned short h[4], l[4];
#pragma unroll
    for (int j = 0; j < 4; j++) {
        h[j] = f2bf_rne(x[j]);
        const float hf = __uint_as_float(((unsigned)h[j]) << 16);
        l[j] = f2bf_rne(x[j] - hf);
    }
    *(ushort4*)&fhi[i] = make_ushort4(h[0], h[1], h[2], h[3]);
    *(ushort4*)&flo[i] = make_ushort4(l[0], l[1], l[2], l[3]);
}

#define AS1(p) ((const __attribute__((address_space(1))) unsigned int*)(p))
#define AS3(p) ((__attribute__((address_space(3))) unsigned int*)(p))

__device__ __forceinline__ void gll16(const unsigned short* g, unsigned short* l) {
    __builtin_amdgcn_global_load_lds(AS1(g), AS3(l), 16, 0, 0);
}

// Fused bf16x3 Gram + batch-hard mining. ONE WAVE PER BLOCK (no barriers):
// 2080 triangle tiles of 64x64, K_STEP=32, single-buffered 16KB LDS ->
// ~10 blocks/CU all co-resident (no tail); latency hidden by inter-wave TLP.
// XOR chunk swizzle (key = (row>>1)&3) on global source + frag reads keeps
// ds_read_b128 conflict-free (verified 0 conflicts in R3).
// Last block (device-scope counter) computes the final scalar loss.
__launch_bounds__(64, 2)
__global__ void gram_mine_kernel(const unsigned short* __restrict__ fhi,
                                 const unsigned short* __restrict__ flo,
                                 const int* __restrict__ labels,
                                 unsigned* __restrict__ hp,
                                 unsigned* __restrict__ hn,
                                 unsigned* __restrict__ counter,
                                 float* __restrict__ out) {
    __shared__ __align__(16) unsigned short As_hi[64][32];
    __shared__ __align__(16) unsigned short As_lo[64][32];
    __shared__ __align__(16) unsigned short Bs_hi[64][32];
    __shared__ __align__(16) unsigned short Bs_lo[64][32];

    const int lane = threadIdx.x;   // 0..63

    // XCD-aware bijective swizzle, then triangle unrank (bx <= by)
    const int bid = blockIdx.x;
    const int t = (bid & 7) * BPX + (bid >> 3);
    int by = (int)((sqrtf(8.0f * (float)t + 1.0f) - 1.0f) * 0.5f);
    while ((by + 1) * (by + 2) / 2 <= t) by++;
    while (by * (by + 1) / 2 > t) by--;
    const int bx = t - by * (by + 1) / 2;
    const int r0 = by * 64;
    const int c0 = bx * 64;
    const bool offdiag = (by != bx);

    // staging: lane l -> LDS row 16q+(l>>2), 16B slot (l&3) [linear dest];
    // source chunk pre-swizzled: slot s of row r holds global chunk s^((r>>1)&3)
    const int srow = lane >> 2;
    const int scol = ((lane & 3) ^ ((lane >> 3) & 3)) * 8;

    f32x4 acc[4][4];
#pragma unroll
    for (int i = 0; i < 4; i++)
#pragma unroll
        for (int j = 0; j < 4; j++) acc[i][j] = (f32x4)(0.0f);

    const int frow = lane & 15;           // fragment row/col within 16
    const int fkg = lane >> 4;            // k-group 0..3
    const int ch = (fkg ^ ((frow >> 1) & 3)) * 8;  // swizzled read chunk (row-parity key)

    for (int kt = 0; kt < 16; ++kt) {
        const int k0 = kt * 32;
        __builtin_amdgcn_sched_barrier(0);   // keep STAGE after prev iter's MFMAs
#pragma unroll
        for (int q = 0; q < 4; ++q) {
            const int rr = 16 * q + srow;
            gll16(&fhi[(size_t)(r0 + rr) * DIM + k0 + scol], &As_hi[16 * q][0] + lane * 8);
            gll16(&flo[(size_t)(r0 + rr) * DIM + k0 + scol], &As_lo[16 * q][0] + lane * 8);
            gll16(&fhi[(size_t)(c0 + rr) * DIM + k0 + scol], &Bs_hi[16 * q][0] + lane * 8);
            gll16(&flo[(size_t)(c0 + rr) * DIM + k0 + scol], &Bs_lo[16 * q][0] + lane * 8);
        }
        asm volatile("s_waitcnt vmcnt(0)" ::: "memory");
        __builtin_amdgcn_sched_barrier(0);

        bf16x8 ah[4], al[4], bh[4], bl[4];
#pragma unroll
        for (int mi = 0; mi < 4; mi++) {
            const int r = mi * 16 + frow;
            ah[mi] = *(const bf16x8*)&As_hi[r][ch];
            al[mi] = *(const bf16x8*)&As_lo[r][ch];
            bh[mi] = *(const bf16x8*)&Bs_hi[r][ch];
            bl[mi] = *(const bf16x8*)&Bs_lo[r][ch];
        }
        // 3 passes, same accumulation order as R3 (bit-identical results)
#pragma unroll
        for (int mi = 0; mi < 4; mi++)
#pragma unroll
            for (int nj = 0; nj < 4; nj++)
                acc[mi][nj] = __builtin_amdgcn_mfma_f32_16x16x32_bf16(ah[mi], bh[nj], acc[mi][nj], 0, 0, 0);
#pragma unroll
        for (int mi = 0; mi < 4; mi++)
#pragma unroll
            for (int nj = 0; nj < 4; nj++)
                acc[mi][nj] = __builtin_amdgcn_mfma_f32_16x16x32_bf16(ah[mi], bl[nj], acc[mi][nj], 0, 0, 0);
#pragma unroll
        for (int mi = 0; mi < 4; mi++)
#pragma unroll
            for (int nj = 0; nj < 4; nj++)
                acc[mi][nj] = __builtin_amdgcn_mfma_f32_16x16x32_bf16(al[mi], bh[nj], acc[mi][nj], 0, 0, 0);
    }

    // ---- fused batch-hard mining (C frag: col = frow, row = fkg*4 + reg) ----
    int rlab[4][4], clab[4];
#pragma unroll
    for (int mi = 0; mi < 4; mi++)
#pragma unroll
        for (int rg = 0; rg < 4; rg++)
            rlab[mi][rg] = labels[r0 + mi * 16 + fkg * 4 + rg];
#pragma unroll
    for (int nj = 0; nj < 4; nj++)
        clab[nj] = labels[c0 + nj * 16 + frow];

    float pmax[4][4], nmin[4][4];   // row-anchor
    float cpmax[4], cnmin[4];       // col-anchor (symmetric pass)
#pragma unroll
    for (int mi = 0; mi < 4; mi++)
#pragma unroll
        for (int rg = 0; rg < 4; rg++) { pmax[mi][rg] = -BIG; nmin[mi][rg] = BIG; }
#pragma unroll
    for (int nj = 0; nj < 4; nj++) { cpmax[nj] = -BIG; cnmin[nj] = BIG; }

#pragma unroll
    for (int mi = 0; mi < 4; mi++)
#pragma unroll
        for (int nj = 0; nj < 4; nj++)
#pragma unroll
            for (int rg = 0; rg < 4; rg++) {
                const float dist = 1.0f - acc[mi][nj][rg];
                if (rlab[mi][rg] == clab[nj]) {
                    if (dist > EPS) {
                        pmax[mi][rg] = fmaxf(pmax[mi][rg], dist);
                        cpmax[nj] = fmaxf(cpmax[nj], dist);
                    }
                } else {
                    nmin[mi][rg] = fminf(nmin[mi][rg], dist);
                    cnmin[nj] = fminf(cnmin[nj], dist);
                }
            }

    // row-anchor reduce across 16 cols (lanes with same fkg)
#pragma unroll
    for (int off = 8; off; off >>= 1) {
#pragma unroll
        for (int mi = 0; mi < 4; mi++)
#pragma unroll
            for (int rg = 0; rg < 4; rg++) {
                pmax[mi][rg] = fmaxf(pmax[mi][rg], __shfl_xor(pmax[mi][rg], off, 16));
                nmin[mi][rg] = fminf(nmin[mi][rg], __shfl_xor(nmin[mi][rg], off, 16));
            }
    }
    if (frow == 0) {
#pragma unroll
        for (int mi = 0; mi < 4; mi++)
#pragma unroll
            for (int rg = 0; rg < 4; rg++) {
                const int R = r0 + mi * 16 + fkg * 4 + rg;
                atomicMax(&hp[R], enc_f(pmax[mi][rg]));
                atomicMin(&hn[R], enc_f(nmin[mi][rg]));
            }
    }

    // col-anchor reduce across the 16 rows (xor 16, 32); skip on diagonal
    if (offdiag) {
#pragma unroll
        for (int nj = 0; nj < 4; nj++) {
            cpmax[nj] = fmaxf(cpmax[nj], __shfl_xor(cpmax[nj], 16, 64));
            cpmax[nj] = fmaxf(cpmax[nj], __shfl_xor(cpmax[nj], 32, 64));
            cnmin[nj] = fminf(cnmin[nj], __shfl_xor(cnmin[nj], 16, 64));
            cnmin[nj] = fminf(cnmin[nj], __shfl_xor(cnmin[nj], 32, 64));
        }
        if (fkg == 0) {
#pragma unroll
            for (int nj = 0; nj < 4; nj++) {
                const int C = c0 + nj * 16 + frow;
                atomicMax(&hp[C], enc_f(cpmax[nj]));
                atomicMin(&hn[C], enc_f(cnmin[nj]));
            }
        }
    }

    // ---- last-block finalize (release/acquire via device-scope counter) ----
    __threadfence();
    int old = 0;
    if (lane == 0) old = (int)atomicAdd(counter, 1u);
    old = __shfl(old, 0, 64);
    if (old == NBLOCKS - 1) {
        __threadfence();
        float sum = 0.0f;
        int cnt = 0;
        for (int i = lane; i < NROWS; i += 64) {
            const float p = dec_f(__hip_atomic_load(&hp[i], __ATOMIC_RELAXED, __HIP_MEMORY_SCOPE_AGENT));
            const float n = dec_f(__hip_atomic_load(&hn[i], __ATOMIC_RELAXED, __HIP_MEMORY_SCOPE_AGENT));
            const float tl = p - n + MARGIN;
            if (tl > 0.0f) { sum += tl; cnt++; }
        }
#pragma unroll
        for (int off = 32; off; off >>= 1) {
            sum += __shfl_down(sum, off, 64);
            cnt += __shfl_down(cnt, off, 64);
        }
        if (lane == 0) out[0] = (cnt > 0) ? sum / (float)cnt : 0.0f;
    }
}

// ---------------- fallback f32 path (used only if ws too small) ----------------
__global__ void init_kernel(unsigned* __restrict__ hp, unsigned* __restrict__ hn) {
    int i = blockIdx.x * blockDim.x + threadIdx.x;
    if (i < NROWS) {
        hp[i] = enc_f(-BIG);
        hn[i] = enc_f(BIG);
    }
}

__launch_bounds__(256, 2)
__global__ void dist_mine_kernel(const float* __restrict__ feats,
                                 const int* __restrict__ labels,
                                 unsigned* __restrict__ hp,
                                 unsigned* __restrict__ hn) {
    __shared__ float As[64][68];
    __shared__ float Bs[64][68];
    const int tid = threadIdx.x;
    const int tx = tid & 15;
    const int ty = tid >> 4;
    const int r0 = blockIdx.y * 64;
    const int c0 = blockIdx.x * 256;
    const int srow = tid >> 4;
    const int scol4 = (tid & 15) * 4;
    int rlab[4];
#pragma unroll
    for (int i = 0; i < 4; i++) rlab[i] = labels[r0 + ty + 16 * i];
    float pmax[4] = {-BIG, -BIG, -BIG, -BIG};
    float nmin[4] = {BIG, BIG, BIG, BIG};
    for (int ct = 0; ct < 4; ++ct) {
        const int c = c0 + ct * 64;
        int clab[4];
#pragma unroll
        for (int j = 0; j < 4; j++) clab[j] = labels[c + tx + 16 * j];
        float acc[4][4];
#pragma unroll
        for (int i = 0; i < 4; i++)
#pragma unroll
            for (int j = 0; j < 4; j++) acc[i][j] = 0.0f;
        for (int kt = 0; kt < 8; ++kt) {
            const int kbase = kt * 64;
#pragma unroll
            for (int p = 0; p < 4; p++) {
                const int row = srow + p * 16;
                *(float4*)&As[row][scol4] = *(const float4*)&feats[(size_t)(r0 + row) * DIM + kbase + scol4];
                *(float4*)&Bs[row][scol4] = *(const float4*)&feats[(size_t)(c + row) * DIM + kbase + scol4];
            }
            __syncthreads();
#pragma unroll
            for (int kk = 0; kk < 64; kk += 4) {
                float4 a[4], b[4];
#pragma unroll
                for (int i = 0; i < 4; i++) a[i] = *(const float4*)&As[ty + 16 * i][kk];
#pragma unroll
                for (int j = 0; j < 4; j++) b[j] = *(const float4*)&Bs[tx + 16 * j][kk];
#pragma unroll
                for (int i = 0; i < 4; i++)
#pragma unroll
                    for (int j = 0; j < 4; j++) {
                        acc[i][j] = fmaf(a[i].x, b[j].x, acc[i][j]);
                        acc[i][j] = fmaf(a[i].y, b[j].y, acc[i][j]);
                        acc[i][j] = fmaf(a[i].z, b[j].z, acc[i][j]);
                        acc[i][j] = fmaf(a[i].w, b[j].w, acc[i][j]);
                    }
            }
            __syncthreads();
        }
#pragma unroll
        for (int i = 0; i < 4; i++)
#pragma unroll
            for (int j = 0; j < 4; j++) {
                const float dist = 1.0f - acc[i][j];
                if (rlab[i] == clab[j]) {
                    if (dist > EPS) pmax[i] = fmaxf(pmax[i], dist);
                } else {
                    nmin[i] = fminf(nmin[i], dist);
                }
            }
    }
#pragma unroll
    for (int off = 8; off; off >>= 1) {
#pragma unroll
        for (int i = 0; i < 4; i++) {
            pmax[i] = fmaxf(pmax[i], __shfl_xor(pmax[i], off, 16));
            nmin[i] = fminf(nmin[i], __shfl_xor(nmin[i], off, 16));
        }
    }
    if (tx == 0) {
#pragma unroll
        for (int i = 0; i < 4; i++) {
            const int r = r0 + ty + 16 * i;
            atomicMax(&hp[r], enc_f(pmax[i]));
            atomicMin(&hn[r], enc_f(nmin[i]));
        }
    }
}

__global__ void finalize_kernel(const unsigned* __restrict__ hp,
                                const unsigned* __restrict__ hn,
                                float* __restrict__ out) {
    __shared__ float ssum[4];
    __shared__ int scnt[4];
    const int tid = threadIdx.x;
    float sum = 0.0f;
    int cnt = 0;
    for (int i = tid; i < NROWS; i += 256) {
        const float p = dec_f(hp[i]);
        const float n = dec_f(hn[i]);
        const float tl = p - n + MARGIN;
        if (tl > 0.0f) { sum += tl; cnt++; }
    }
#pragma unroll
    for (int off = 32; off; off >>= 1) {
        sum += __shfl_down(sum, off, 64);
        cnt += __shfl_down(cnt, off, 64);
    }
    const int wv = tid >> 6, lane = tid & 63;
    if (lane == 0) { ssum[wv] = sum; scnt[wv] = cnt; }
    __syncthreads();
    if (tid == 0) {
        const float s = ssum[0] + ssum[1] + ssum[2] + ssum[3];
        const int c = scnt[0] + scnt[1] + scnt[2] + scnt[3];
        out[0] = (c > 0) ? s / (float)c : 0.0f;
    }
}

extern "C" void kernel_launch(void* const* d_in, const int* in_sizes, int n_in,
                              void* d_out, int out_size, void* d_ws, size_t ws_size,
                              hipStream_t stream) {
    const float* feats = (const float*)d_in[0];
    const int* labels = (const int*)d_in[1];
    float* out = (float*)d_out;

    unsigned* hp = (unsigned*)d_ws;                                   // 4096 u32
    unsigned* hn = hp + NROWS;                                        // 4096 u32
    unsigned* counter = hn + NROWS;                                   // 1 u32
    unsigned short* fhi = (unsigned short*)((char*)d_ws + 33024);     // 256B-aligned
    unsigned short* flo = fhi + (size_t)NROWS * DIM;

    const size_t need = 33024 + (size_t)NROWS * DIM * 2 * 2;

    if (ws_size >= need) {
        prep_kernel<<<(NROWS * DIM) / (256 * 4), 256, 0, stream>>>(feats, fhi, flo, hp, hn, counter);
        gram_mine_kernel<<<NBLOCKS, 64, 0, stream>>>(fhi, flo, labels, hp, hn, counter, out);
    } else {
        init_kernel<<<16, 256, 0, stream>>>(hp, hn);
        dim3 grid(16, 64);
        dist_mine_kernel<<<grid, 256, 0, stream>>>(feats, labels, hp, hn);
        finalize_kernel<<<1, 256, 0, stream>>>(hp, hn, out);
    }
}